// Round 5
// baseline (11117.519 us; speedup 1.0000x reference)
//
#include <hip/hip_runtime.h>

#define HID   1024
#define TLEN  512
#define VOC   128
#define NR    32          // reset-gate blocks: 32 cols each (r, rh)
#define NZ    32          // update blocks: 32 cols each (z, h_tilde, h_new)
#define NO    8           // out-head blocks: 16 vocab cols each
#define NBLK  (NR + NZ + NO)
#define LDSK  1032        // padded LDS row stride (16B-aligned rows)
#define HBUF  (64 * HID)  // one h buffer (elements)
#define NHB   8           // h buffer rotation depth

typedef __bf16 bf16_t;
typedef __attribute__((ext_vector_type(8))) __bf16 bf16x8;
typedef __attribute__((ext_vector_type(4))) float  f32x4;

__device__ __forceinline__ float sigmoid_fast(float x) {
  return 1.0f / (1.0f + __expf(-x));
}
__device__ __forceinline__ float tanh_fast(float x) {
  float e = __expf(-2.0f * x);
  return (1.0f - e) / (1.0f + e);
}

union FragU { unsigned long long u[2]; bf16x8 v; };
union PairU { bf16_t b[2]; unsigned u; };

// MALL-coherent (agent-scope relaxed atomic) accesses. These compile to plain
// coalesced global_load/store with L2-bypass bits -- no fences needed, ever.
__device__ __forceinline__ bf16x8 ld_frag(const bf16_t* p) {
  FragU x;
  x.u[0] = __hip_atomic_load((const unsigned long long*)p,       __ATOMIC_RELAXED, __HIP_MEMORY_SCOPE_AGENT);
  x.u[1] = __hip_atomic_load((const unsigned long long*)(p + 4), __ATOMIC_RELAXED, __HIP_MEMORY_SCOPE_AGENT);
  return x.v;
}
__device__ __forceinline__ void st_pair(bf16_t* p, float f0, float f1) {
  PairU c;
  c.b[0] = (bf16_t)f0;
  c.b[1] = (bf16_t)f1;
  __hip_atomic_store((unsigned*)p, c.u, __ATOMIC_RELAXED, __HIP_MEMORY_SCOPE_AGENT);
}
__device__ __forceinline__ PairU ld_pair(const bf16_t* p) {
  PairU c;
  c.u = __hip_atomic_load((const unsigned*)p, __ATOMIC_RELAXED, __HIP_MEMORY_SCOPE_AGENT);
  return c;
}

// wave 0 polls 32 packed flags (coalesced, relaxed); other waves park at the
// barrier. No acquire fence: all cross-block data is read via MALL-coherent
// atomics, so there is no stale cache state to invalidate.
__device__ __forceinline__ void wait32(const unsigned* flags, unsigned tgt) {
  if ((threadIdx.x >> 6) == 0) {
    const int lane = threadIdx.x & 63;
    for (;;) {
      unsigned g = tgt;
      if (lane < 32)
        g = __hip_atomic_load(&flags[lane], __ATOMIC_RELAXED, __HIP_MEMORY_SCOPE_AGENT);
      if (__all(g >= tgt)) break;
      __builtin_amdgcn_s_sleep(1);
    }
  }
  __syncthreads();
}

// combined wait: rfl[0..32) >= tgt AND ofl[0..8) >= otgt
__device__ __forceinline__ void wait_rf_of(const unsigned* rfl, const unsigned* ofl,
                                           unsigned tgt, unsigned otgt) {
  if ((threadIdx.x >> 6) == 0) {
    const int lane = threadIdx.x & 63;
    for (;;) {
      bool ok = true;
      if (lane < 32)
        ok = __hip_atomic_load(&rfl[lane], __ATOMIC_RELAXED, __HIP_MEMORY_SCOPE_AGENT) >= tgt;
      else if (lane < 40)
        ok = __hip_atomic_load(&ofl[lane - 32], __ATOMIC_RELAXED, __HIP_MEMORY_SCOPE_AGENT) >= otgt;
      if (__all(ok)) break;
      __builtin_amdgcn_s_sleep(1);
    }
  }
  __syncthreads();
}

// publish: __syncthreads drains every wave's write-through stores (vmcnt(0)
// before s_barrier => data is at the MALL), then one RELAXED flag store.
// No release fence => no buffer_wbl2 L2 walk.
__device__ __forceinline__ void publish(unsigned* f, unsigned v) {
  __syncthreads();
  if (threadIdx.x == 0)
    __hip_atomic_store(f, v, __ATOMIC_RELAXED, __HIP_MEMORY_SCOPE_AGENT);
}

__global__ void __launch_bounds__(256)
gru_nofence(const int* __restrict__ X,
            const float* __restrict__ Wr_x, const float* __restrict__ Wr_h, const float* __restrict__ b_r,
            const float* __restrict__ Wz_x, const float* __restrict__ Wz_h, const float* __restrict__ b_z,
            const float* __restrict__ Wh_x, const float* __restrict__ Wh_h, const float* __restrict__ b_h,
            const float* __restrict__ W_o,  const float* __restrict__ b_o,
            float* __restrict__ out,
            bf16_t* __restrict__ h0, bf16_t* __restrict__ rh_bf,
            unsigned* __restrict__ flags)
{
  __shared__ __align__(16) bf16_t Wbuf[2 * 32 * LDSK];  // 132KB

  unsigned* hfl = flags;        // [0,32)   published by ZH blocks
  unsigned* rfl = flags + 64;   // [64,96)  published by R blocks
  unsigned* ofl = flags + 128;  // [128,136) published by out heads

  const int blk  = blockIdx.x;
  const int tid  = threadIdx.x;
  const int lane = tid & 63;
  const int wv   = tid >> 6;     // wave -> batch tile [wv*16, +16)
  const int n16  = lane & 15;    // A-row(batch) / B-col / D-col within tile
  const int q    = lane >> 4;    // k-subchunk / D-row quad

  const int aoff = (wv * 16 + n16) * HID + q * 8;  // A-frag offset in h/rh

  int bi[4];
#pragma unroll
  for (int i = 0; i < 4; ++i) bi[i] = wv * 16 + q * 4 + i;

  if (blk < NR) {
    // ============ R block: 32 cols of r -> rh, write-through ===============
    const int c0 = blk * 32;
    // column remap: LDS tile0 row p <- col 2p, tile1 row p <- col 2p+1,
    // so lane n16's two D values are ADJACENT cols (one 4B store).
    for (int idx = tid; idx < 32 * HID; idx += 256) {
      int n = idx & 31, k = idx >> 5;
      Wbuf[((n & 1) * 16 + (n >> 1)) * LDSK + k] = (bf16_t)Wr_h[k * HID + c0 + n];
    }
    __syncthreads();

    const int j0 = c0 + 2 * n16;            // even col; j0+1 is the odd one
    const float br0 = b_r[j0], br1 = b_r[j0 + 1];
    const bf16_t* w0 = &Wbuf[n16 * LDSK + q * 8];
    const bf16_t* w1 = &Wbuf[(16 + n16) * LDSK + q * 8];

    for (int t = 0; t < TLEN; ++t) {
      wait32(hfl, (unsigned)t);
      const bf16_t* hslot = h0 + (t & (NHB - 1)) * HBUF;
      int xb[4]; float gx0[4], gx1[4];
#pragma unroll
      for (int i = 0; i < 4; ++i) {
        xb[i]  = X[bi[i] * TLEN + t];
        gx0[i] = Wr_x[xb[i] * HID + j0];
        gx1[i] = Wr_x[xb[i] * HID + j0 + 1];
      }
      const bf16_t* hrow = hslot + aoff;
      f32x4 a0 = {0.f,0.f,0.f,0.f}, a1 = {0.f,0.f,0.f,0.f};
#pragma unroll 8
      for (int kk = 0; kk < 32; ++kk) {
        bf16x8 a  = ld_frag(hrow + kk * 32);
        bf16x8 b0 = *reinterpret_cast<const bf16x8*>(w0 + kk * 32);
        bf16x8 b1 = *reinterpret_cast<const bf16x8*>(w1 + kk * 32);
        a0 = __builtin_amdgcn_mfma_f32_16x16x32_bf16(a, b0, a0, 0, 0, 0);
        a1 = __builtin_amdgcn_mfma_f32_16x16x32_bf16(a, b1, a1, 0, 0, 0);
      }
#pragma unroll
      for (int i = 0; i < 4; ++i) {
        int b = bi[i];
        float r0 = sigmoid_fast(a0[i] + br0 + gx0[i]);
        float r1 = sigmoid_fast(a1[i] + br1 + gx1[i]);
        PairU hp = ld_pair(hslot + b * HID + j0);
        st_pair(rh_bf + b * HID + j0, r0 * (float)hp.b[0], r1 * (float)hp.b[1]);
      }
      publish(&rfl[blk], (unsigned)(t + 1));
    }
  } else if (blk < NR + NZ) {
    // ============ ZH block: 32 cols of z, h_tilde, h_new ===================
    const int zb = blk - NR;
    const int c0 = zb * 32;
    for (int idx = tid; idx < 32 * HID; idx += 256) {
      int n = idx & 31, k = idx >> 5;
      int r = (n & 1) * 16 + (n >> 1);
      Wbuf[r * LDSK + k]             = (bf16_t)Wz_h[k * HID + c0 + n];
      Wbuf[32 * LDSK + r * LDSK + k] = (bf16_t)Wh_h[k * HID + c0 + n];
    }
    __syncthreads();

    const int j0 = c0 + 2 * n16;
    const float bz0 = b_z[j0], bz1 = b_z[j0 + 1];
    const float bh0 = b_h[j0], bh1 = b_h[j0 + 1];
    const bf16_t* wz0 = &Wbuf[n16 * LDSK + q * 8];
    const bf16_t* wz1 = &Wbuf[(16 + n16) * LDSK + q * 8];
    const bf16_t* wh0 = &Wbuf[32 * LDSK + n16 * LDSK + q * 8];
    const bf16_t* wh1 = &Wbuf[32 * LDSK + (16 + n16) * LDSK + q * 8];
    const bf16_t* rhrow = rh_bf + aoff;

    f32x4 hm0 = {0.f,0.f,0.f,0.f}, hm1 = {0.f,0.f,0.f,0.f};  // fp32 h master

    for (int t = 0; t < TLEN; ++t) {
      // ---- z phase (needs only h(t); overlaps R's work) ----
      wait32(hfl, (unsigned)t);
      int xb[4]; float gz0[4], gz1[4], gh0[4], gh1[4];
#pragma unroll
      for (int i = 0; i < 4; ++i) {
        xb[i]  = X[bi[i] * TLEN + t];
        gz0[i] = Wz_x[xb[i] * HID + j0];
        gz1[i] = Wz_x[xb[i] * HID + j0 + 1];
        gh0[i] = Wh_x[xb[i] * HID + j0];
        gh1[i] = Wh_x[xb[i] * HID + j0 + 1];
      }
      const bf16_t* hrow = h0 + (t & (NHB - 1)) * HBUF + aoff;
      f32x4 az0 = {0.f,0.f,0.f,0.f}, az1 = {0.f,0.f,0.f,0.f};
#pragma unroll 8
      for (int kk = 0; kk < 32; ++kk) {
        bf16x8 a  = ld_frag(hrow + kk * 32);
        bf16x8 b0 = *reinterpret_cast<const bf16x8*>(wz0 + kk * 32);
        bf16x8 b1 = *reinterpret_cast<const bf16x8*>(wz1 + kk * 32);
        az0 = __builtin_amdgcn_mfma_f32_16x16x32_bf16(a, b0, az0, 0, 0, 0);
        az1 = __builtin_amdgcn_mfma_f32_16x16x32_bf16(a, b1, az1, 0, 0, 0);
      }
      f32x4 z0, z1;
#pragma unroll
      for (int i = 0; i < 4; ++i) {
        z0[i] = sigmoid_fast(az0[i] + bz0 + gz0[i]);
        z1[i] = sigmoid_fast(az1[i] + bz1 + gz1[i]);
      }

      // ---- h_tilde phase (needs full rh(t); WAR guard vs out heads) ----
      unsigned otgt = (t >= NHB - 1) ? (unsigned)(t - (NHB - 1)) : 0u;
      wait_rf_of(rfl, ofl, (unsigned)(t + 1), otgt);
      f32x4 ah0 = {0.f,0.f,0.f,0.f}, ah1 = {0.f,0.f,0.f,0.f};
#pragma unroll 8
      for (int kk = 0; kk < 32; ++kk) {
        bf16x8 a  = ld_frag(rhrow + kk * 32);
        bf16x8 b0 = *reinterpret_cast<const bf16x8*>(wh0 + kk * 32);
        bf16x8 b1 = *reinterpret_cast<const bf16x8*>(wh1 + kk * 32);
        ah0 = __builtin_amdgcn_mfma_f32_16x16x32_bf16(a, b0, ah0, 0, 0, 0);
        ah1 = __builtin_amdgcn_mfma_f32_16x16x32_bf16(a, b1, ah1, 0, 0, 0);
      }
      bf16_t* hnext = h0 + ((t + 1) & (NHB - 1)) * HBUF;
#pragma unroll
      for (int i = 0; i < 4; ++i) {
        int b = bi[i];
        float ht0 = tanh_fast(ah0[i] + bh0 + gh0[i]);
        float ht1 = tanh_fast(ah1[i] + bh1 + gh1[i]);
        float hn0 = z0[i] * hm0[i] + (1.f - z0[i]) * ht0;
        float hn1 = z1[i] * hm1[i] + (1.f - z1[i]) * ht1;
        hm0[i] = hn0; hm1[i] = hn1;
        st_pair(hnext + b * HID + j0, hn0, hn1);
      }
      publish(&hfl[zb], (unsigned)(t + 1));
    }
  } else {
    // ============ out head: out[t-1] = h_t @ W_o + b_o =====================
    const int ob = blk - NR - NZ;
    const int c0 = ob * 16;
    for (int idx = tid; idx < 16 * HID; idx += 256) {
      int n = idx & 15, k = idx >> 4;
      Wbuf[n * LDSK + k] = (bf16_t)W_o[k * VOC + c0 + n];
    }
    __syncthreads();

    const int v = c0 + n16;
    const float bos = b_o[v];
    const bf16_t* w0 = &Wbuf[n16 * LDSK + q * 8];

    for (int t = 1; t <= TLEN; ++t) {
      wait32(hfl, (unsigned)t);
      const bf16_t* hrow = h0 + (t & (NHB - 1)) * HBUF + aoff;
      f32x4 acc = {0.f,0.f,0.f,0.f};
#pragma unroll 8
      for (int kk = 0; kk < 32; ++kk) {
        bf16x8 a = ld_frag(hrow + kk * 32);
        bf16x8 b = *reinterpret_cast<const bf16x8*>(w0 + kk * 32);
        acc = __builtin_amdgcn_mfma_f32_16x16x32_bf16(a, b, acc, 0, 0, 0);
      }
#pragma unroll
      for (int i = 0; i < 4; ++i) {
        int b = bi[i];
        out[(b * TLEN + (t - 1)) * VOC + v] = acc[i] + bos;  // cached store
      }
      publish(&ofl[ob], (unsigned)t);  // h_t reads drained by publish's barrier
    }
  }
}

extern "C" void kernel_launch(void* const* d_in, const int* in_sizes, int n_in,
                              void* d_out, int out_size, void* d_ws, size_t ws_size,
                              hipStream_t stream) {
  const int*   X    = (const int*)d_in[0];
  const float* Wr_x = (const float*)d_in[1];
  const float* Wr_h = (const float*)d_in[2];
  const float* b_r  = (const float*)d_in[3];
  const float* Wz_x = (const float*)d_in[4];
  const float* Wz_h = (const float*)d_in[5];
  const float* b_z  = (const float*)d_in[6];
  const float* Wh_x = (const float*)d_in[7];
  const float* Wh_h = (const float*)d_in[8];
  const float* b_h  = (const float*)d_in[9];
  const float* W_o  = (const float*)d_in[10];
  const float* b_o  = (const float*)d_in[11];

  char* ws = (char*)d_ws;
  // layout: [flags 4KB | h 8 x 128KB | rh 128KB]
  unsigned* flags = (unsigned*)ws;
  bf16_t*   h0    = (bf16_t*)(ws + 4096);
  bf16_t*   rh_bf = (bf16_t*)(ws + 4096 + NHB * HBUF * sizeof(bf16_t));

  // zero flags + h slot 0 (h(0)=0); rh and slots 1..7 are written before read
  hipMemsetAsync(ws, 0, 4096 + HBUF * sizeof(bf16_t), stream);

  gru_nofence<<<NBLK, 256, 0, stream>>>(
      X, Wr_x, Wr_h, b_r, Wz_x, Wz_h, b_z, Wh_x, Wh_h, b_h, W_o, b_o,
      (float*)d_out, h0, rh_bf, flags);
}